// Round 9
// baseline (56.720 us; speedup 1.0000x reference)
//
#include <hip/hip_runtime.h>
#include <hip/hip_fp16.h>
#include <cstddef>
#include <cstdint>

#define D_IN  4096
#define D_OUT 4096
#define BB    64
#define NBLK  256   // hist/scatter blocks
#define PPB   1024  // points per block (NBLK*PPB = N)
#define CAP   128   // slots per column: mean 64, sigma 8 -> 8-sigma headroom

// ws layout: [hist: NBLK*D_OUT u32 = 4MB][bins: D_OUT*CAP*8B = 4MB]
//            [xP: D_IN*BB*8B = 2MB][colCnt: 16KB]
// Counting sort by floor-col replaces all global returning atomics (R8's ~25us
// rock) with LDS atomics. Entry format (8B, same as R8):
//   .x: rowf[0:11] | rint<<12 | f16(wfr)<<16
//   .y: f16(w_this) | f16(w_next)<<16
// rowc = rowf+1-rint, wcr = rint ? 1 : 1-wfr,
// w_this = v*wfc (+ v*wcc if integer col), w_next = v*wcc (0 if integer col).
// xP[row][b] = (x[row][b], x[row+1][b]).
// out[c,:] = sum over entries keyed c of w_this*term + keyed c-1 of w_next*term,
//   term = wfr*x[rowf,:] + wcr*x[rowc,:]  (integer row -> 2*x[rowf], matches ref).

// ---------------------------------------------------------------------------
// K1: per-block LDS histogram of floor-col keys -> hist[blk][c]
// ---------------------------------------------------------------------------
__global__ __launch_bounds__(256) void hist_kernel(
    const float2* __restrict__ ind, uint32_t* __restrict__ hist, int n) {
  __shared__ uint32_t lcnt[D_OUT];
  const int tid = threadIdx.x;
  for (int c = tid; c < D_OUT; c += 256) lcnt[c] = 0u;
  __syncthreads();
  const int base = blockIdx.x * PPB;
#pragma unroll
  for (int i = 0; i < PPB / 256; i++) {
    int p = base + i * 256 + tid;
    if (p < n) {
      int key = (int)floorf(ind[p].y);
      atomicAdd(&lcnt[key], 1u);
    }
  }
  __syncthreads();
  for (int c = tid; c < D_OUT; c += 256)
    hist[(size_t)blockIdx.x * D_OUT + c] = lcnt[c];
}

// ---------------------------------------------------------------------------
// K2: blocks 0..15: transform hist into per-(blk,col) base offsets
//     (running sum along blk, seeded at c*CAP) and emit colCnt.
//     blocks 16..: zero out, build xP pair table.
// ---------------------------------------------------------------------------
__global__ __launch_bounds__(256) void scan_prep_kernel(
    uint32_t* __restrict__ hist, uint32_t* __restrict__ colCnt,
    const float* __restrict__ x, float2* __restrict__ xP,
    float* __restrict__ out, int nblk) {
  const int blk = blockIdx.x;
  if (blk < 16) {
    int c = blk * 256 + threadIdx.x;      // one col per thread
    uint32_t run = (uint32_t)c * CAP;
#pragma unroll 4
    for (int b = 0; b < nblk; b++) {
      uint32_t t = hist[(size_t)b * D_OUT + c];
      hist[(size_t)b * D_OUT + c] = run;
      run += t;
    }
    colCnt[c] = run - (uint32_t)c * CAP;
  } else {
    int i = (blk - 16) * 256 + threadIdx.x;   // 0 .. 262143
    if (i < D_OUT * BB) {
      out[i] = 0.f;
      float a = x[i];
      float bq = (i + BB < D_IN * BB) ? x[i + BB] : 0.f;
      xP[i] = make_float2(a, bq);
    }
  }
}

// ---------------------------------------------------------------------------
// K3: scatter entries to dense per-col regions. Rank via LDS returning atomic
// (fast), slot = lbase[key] + rank. Zero global returning atomics.
// ---------------------------------------------------------------------------
__global__ __launch_bounds__(256) void scatter_kernel(
    const float2* __restrict__ ind, const float* __restrict__ val,
    const uint32_t* __restrict__ hist, uint2* __restrict__ bins, int n) {
  __shared__ uint32_t lbase[D_OUT];
  __shared__ uint32_t lcnt[D_OUT];
  const int tid = threadIdx.x;
  for (int c = tid; c < D_OUT; c += 256) {
    lbase[c] = hist[(size_t)blockIdx.x * D_OUT + c];
    lcnt[c] = 0u;
  }
  __syncthreads();
  const int base = blockIdx.x * PPB;
#pragma unroll
  for (int i = 0; i < PPB / 256; i++) {
    int p = base + i * 256 + tid;
    if (p >= n) continue;
    float2 rc = ind[p];
    float v = val[p];
    float flr = floorf(rc.x), cer = ceilf(rc.x);
    float flc = floorf(rc.y), cec = ceilf(rc.y);
    // reference weight: prod_k (1 - |corner_k - ind_k|)
    float wfr = 1.0f - (rc.x - flr);
    float wfc = 1.0f - (rc.y - flc);
    float wcc = 1.0f - (cec - rc.y);
    uint32_t rint = ((int)flr == (int)cer) ? 1u : 0u;
    bool cint = ((int)flc == (int)cec);
    float w_this = cint ? v * (wfc + wcc) : v * wfc;
    float w_next = cint ? 0.f : v * wcc;
    uint32_t ex = (uint32_t)(int)flr | (rint << 12)
                | ((uint32_t)__half_as_ushort(__float2half_rn(wfr)) << 16);
    uint32_t ey = (uint32_t)__half_as_ushort(__float2half_rn(w_this))
                | ((uint32_t)__half_as_ushort(__float2half_rn(w_next)) << 16);
    int key = (int)flc;
    uint32_t rank = atomicAdd(&lcnt[key], 1u);
    uint32_t slot = lbase[key] + rank;
    if (slot < ((uint32_t)key + 1u) * CAP)   // overflow guard (P ~ 1e-15)
      bins[slot] = make_uint2(ex, ey);
  }
}

// ---------------------------------------------------------------------------
// K4: one block (4 waves) per column, lane = b. Entries contiguous with exact
// count. Single visit per entry, one float2 gather (row pair). LDS reduce,
// 2 atomicAdds into pre-zeroed out.
// ---------------------------------------------------------------------------
__global__ __launch_bounds__(256) void accum_kernel(
    const uint32_t* __restrict__ colCnt, const uint2* __restrict__ bins,
    const float2* __restrict__ xP, float* __restrict__ out) {
  __shared__ float red_t[3][BB], red_n[3][BB];
  const int lane = threadIdx.x & 63;
  const int wv   = threadIdx.x >> 6;   // 0..3
  const int col  = blockIdx.x;

  int n = (int)colCnt[col];
  n = n < CAP ? n : CAP;
  const uint2* __restrict__ bin = bins + (size_t)col * CAP;

  // wave wv owns contiguous range [wv*q, min((wv+1)*q, n))
  const int q  = (n + 3) >> 2;
  const int e0 = wv * q;
  const int e1 = (e0 + q) < n ? (e0 + q) : n;

  float acc_t = 0.f, acc_n = 0.f;

#define PROC(Q)                                                           \
  {                                                                       \
    uint32_t ex_ = (Q).x, ey_ = (Q).y;                                    \
    int rowf = (int)(ex_ & 0xfffu);                                       \
    int rint = (int)((ex_ >> 12) & 1u);                                   \
    float wfr = __half2float(__ushort_as_half((ushort)(ex_ >> 16)));      \
    float2 p  = xP[(size_t)rowf * BB + lane];                             \
    float xc  = rint ? p.x : p.y;                                         \
    float wcr = rint ? 1.0f : 1.0f - wfr;                                 \
    float w_t = __half2float(__ushort_as_half((ushort)(ey_ & 0xffffu)));  \
    float w_n = __half2float(__ushort_as_half((ushort)(ey_ >> 16)));      \
    float term = fmaf(wfr, p.x, wcr * xc);                                \
    acc_t = fmaf(w_t, term, acc_t);                                       \
    acc_n = fmaf(w_n, term, acc_n);                                       \
  }

  int e = e0;
  for (; e + 8 <= e1; e += 8) {
    uint2 qv[8];
#pragma unroll
    for (int t = 0; t < 8; t++) qv[t] = bin[e + t];
#pragma unroll
    for (int t = 0; t < 8; t++) PROC(qv[t]);
  }
  for (; e < e1; e++) {
    uint2 qv = bin[e];
    PROC(qv)
  }
#undef PROC

  if (wv > 0) {
    red_t[wv - 1][lane] = acc_t;
    red_n[wv - 1][lane] = acc_n;
  }
  __syncthreads();
  if (wv == 0) {
    acc_t += red_t[0][lane] + red_t[1][lane] + red_t[2][lane];
    acc_n += red_n[0][lane] + red_n[1][lane] + red_n[2][lane];
    atomicAdd(&out[(size_t)col * BB + lane], acc_t);
    if (col + 1 < D_OUT) atomicAdd(&out[(size_t)(col + 1) * BB + lane], acc_n);
  }
}

// ---------------------------------------------------------------------------
// Fallback (ws too small): direct atomic scatter into out (f32).
// ---------------------------------------------------------------------------
__global__ __launch_bounds__(256) void direct_kernel(
    const float2* __restrict__ ind, const float* __restrict__ val,
    const float* __restrict__ x, float* __restrict__ out, int n) {
  int p = blockIdx.x * 4 + (threadIdx.x >> 6);
  if (p >= n) return;
  int lane = threadIdx.x & 63;
  float2 rc = ind[p];
  float v = val[p];
  float flr = floorf(rc.x), cer = ceilf(rc.x);
  float flc = floorf(rc.y), cec = ceilf(rc.y);
  float wfr = 1.0f - (rc.x - flr);
  float wcr = 1.0f - (cer - rc.x);
  float wfc = 1.0f - (rc.y - flc);
  float wcc = 1.0f - (cec - rc.y);
  float xf = x[(size_t)((int)flr) * BB + lane];
  float xc = x[(size_t)((int)cer) * BB + lane];
  float inner = fmaf(wfr, xf, wcr * xc);
  atomicAdd(&out[(size_t)((int)flc) * BB + lane], v * wfc * inner);
  atomicAdd(&out[(size_t)((int)cec) * BB + lane], v * wcc * inner);
}

// ---------------------------------------------------------------------------
extern "C" void kernel_launch(void* const* d_in, const int* in_sizes, int n_in,
                              void* d_out, int out_size, void* d_ws, size_t ws_size,
                              hipStream_t stream) {
  const float2* ind = (const float2*)d_in[0];   // [N,2] f32
  const float*  val = (const float*)d_in[1];    // [N]   f32
  const float*  x   = (const float*)d_in[2];    // [D_IN*B] f32
  float* out = (float*)d_out;                   // [D_OUT*B] f32
  const int N = in_sizes[1];

  const int nblk = (N + PPB - 1) / PPB;                                   // 256
  const size_t hist_bytes = (size_t)NBLK * D_OUT * sizeof(uint32_t);      // 4 MB
  const size_t bin_bytes  = (size_t)D_OUT * CAP * sizeof(uint2);          // 4 MB
  const size_t xp_bytes   = (size_t)D_IN * BB * sizeof(float2);           // 2 MB
  const size_t cc_bytes   = (size_t)D_OUT * sizeof(uint32_t);             // 16 KB

  if (nblk <= NBLK &&
      ws_size >= hist_bytes + bin_bytes + xp_bytes + cc_bytes) {
    uint32_t* hist   = (uint32_t*)d_ws;
    uint2*    bins   = (uint2*)((char*)d_ws + hist_bytes);
    float2*   xP     = (float2*)((char*)d_ws + hist_bytes + bin_bytes);
    uint32_t* colCnt = (uint32_t*)((char*)d_ws + hist_bytes + bin_bytes + xp_bytes);

    hist_kernel<<<nblk, 256, 0, stream>>>(ind, hist, N);
    scan_prep_kernel<<<16 + (D_OUT * BB + 255) / 256, 256, 0, stream>>>(
        hist, colCnt, x, xP, out, nblk);
    scatter_kernel<<<nblk, 256, 0, stream>>>(ind, val, hist, bins, N);
    accum_kernel<<<D_OUT, 256, 0, stream>>>(colCnt, bins, xP, out);
  } else {
    (void)hipMemsetAsync(out, 0, (size_t)out_size * sizeof(float), stream);
    direct_kernel<<<(N + 3) / 4, 256, 0, stream>>>(ind, val, x, out, N);
  }
}

// Round 10
// 44.582 us; speedup vs baseline: 1.2723x; 1.2723x over previous
//
#include <hip/hip_runtime.h>
#include <hip/hip_fp16.h>
#include <cstddef>
#include <cstdint>

#define D_IN  4096
#define D_OUT 4096
#define BB    64
#define NBLK  128   // hist/scatter blocks
#define PPB   2048  // points per block (NBLK*PPB >= N)
#define CAP   128   // slots per column: mean 64, sigma 8 -> 8-sigma headroom

// ws layout: [hist: NBLK*D_OUT u32 = 2MB][bases: NBLK*D_OUT u32 = 2MB]
//            [bins: D_OUT*CAP*8B = 4MB][xP: D_IN*BB*8B = 2MB][colCnt: 16KB]
// Counting sort by floor-col: zero global returning atomics.
// Entry format (8B):
//   .x: rowf[0:11] | rint<<12 | f16(wfr)<<16
//   .y: f16(w_this) | f16(w_next)<<16
// rowc = rowf+1-rint, wcr = rint ? 1 : 1-wfr,
// w_this = v*wfc (+ v*wcc if integer col), w_next = v*wcc (0 if integer col).
// xP[row][b] = (x[row][b], x[row+1][b]).
// out[c,:] = sum entries keyed c: w_this*term  +  keyed c-1: w_next*term,
//   term = wfr*x[rowf,:] + wcr*x[rowc,:] (integer row -> 2*x[rowf], matches ref).

// ---------------------------------------------------------------------------
// K1: per-block LDS histogram of floor-col keys -> hist[blk][c] (coalesced)
// ---------------------------------------------------------------------------
__global__ __launch_bounds__(256) void hist_kernel(
    const float2* __restrict__ ind, uint32_t* __restrict__ hist, int n) {
  __shared__ uint32_t lcnt[D_OUT];
  const int tid = threadIdx.x;
  for (int c = tid; c < D_OUT; c += 256) lcnt[c] = 0u;
  __syncthreads();
  const int base = blockIdx.x * PPB;
#pragma unroll
  for (int i = 0; i < PPB / 256; i++) {
    int p = base + i * 256 + tid;
    if (p < n) {
      int key = (int)floorf(ind[p].y);
      atomicAdd(&lcnt[key], 1u);
    }
  }
  __syncthreads();
  for (int c = tid; c < D_OUT; c += 256)
    hist[(size_t)blockIdx.x * D_OUT + c] = lcnt[c];
}

// ---------------------------------------------------------------------------
// K2: blocks 0..15: per-column prefix sum hist -> bases (SEPARATE array: no
//     store->load aliasing, loads pipeline in chunks of 8), emit colCnt.
//     blocks 16..: zero out, build xP pair table.
// ---------------------------------------------------------------------------
__global__ __launch_bounds__(256) void scan_prep_kernel(
    const uint32_t* __restrict__ hist, uint32_t* __restrict__ bases,
    uint32_t* __restrict__ colCnt, const float* __restrict__ x,
    float2* __restrict__ xP, float* __restrict__ out) {
  const int blk = blockIdx.x;
  if (blk < 16) {
    const int c = blk * 256 + threadIdx.x;      // one column per thread
    uint32_t run = (uint32_t)c * CAP;
#pragma unroll
    for (int b0 = 0; b0 < NBLK; b0 += 8) {
      uint32_t t[8];
#pragma unroll
      for (int j = 0; j < 8; j++) t[j] = hist[(size_t)(b0 + j) * D_OUT + c];
#pragma unroll
      for (int j = 0; j < 8; j++) {
        bases[(size_t)(b0 + j) * D_OUT + c] = run;
        run += t[j];
      }
    }
    colCnt[c] = run - (uint32_t)c * CAP;
  } else {
    int i = (blk - 16) * 256 + threadIdx.x;   // 0 .. 262143
    if (i < D_OUT * BB) {
      out[i] = 0.f;
      float a = x[i];
      float bq = (i + BB < D_IN * BB) ? x[i + BB] : 0.f;
      xP[i] = make_float2(a, bq);
    }
  }
}

// ---------------------------------------------------------------------------
// K3: scatter entries to dense per-col regions. Rank via LDS returning atomic,
// slot = lbase[key] + rank. Zero global returning atomics.
// ---------------------------------------------------------------------------
__global__ __launch_bounds__(256) void scatter_kernel(
    const float2* __restrict__ ind, const float* __restrict__ val,
    const uint32_t* __restrict__ bases, uint2* __restrict__ bins, int n) {
  __shared__ uint32_t lbase[D_OUT];
  __shared__ uint32_t lcnt[D_OUT];
  const int tid = threadIdx.x;
  for (int c = tid; c < D_OUT; c += 256) {
    lbase[c] = bases[(size_t)blockIdx.x * D_OUT + c];
    lcnt[c] = 0u;
  }
  __syncthreads();
  const int base = blockIdx.x * PPB;
#pragma unroll
  for (int i = 0; i < PPB / 256; i++) {
    int p = base + i * 256 + tid;
    if (p >= n) continue;
    float2 rc = ind[p];
    float v = val[p];
    float flr = floorf(rc.x), cer = ceilf(rc.x);
    float flc = floorf(rc.y), cec = ceilf(rc.y);
    // reference weight: prod_k (1 - |corner_k - ind_k|)
    float wfr = 1.0f - (rc.x - flr);
    float wfc = 1.0f - (rc.y - flc);
    float wcc = 1.0f - (cec - rc.y);
    uint32_t rint = ((int)flr == (int)cer) ? 1u : 0u;
    bool cint = ((int)flc == (int)cec);
    float w_this = cint ? v * (wfc + wcc) : v * wfc;
    float w_next = cint ? 0.f : v * wcc;
    uint32_t ex = (uint32_t)(int)flr | (rint << 12)
                | ((uint32_t)__half_as_ushort(__float2half_rn(wfr)) << 16);
    uint32_t ey = (uint32_t)__half_as_ushort(__float2half_rn(w_this))
                | ((uint32_t)__half_as_ushort(__float2half_rn(w_next)) << 16);
    int key = (int)flc;
    uint32_t rank = atomicAdd(&lcnt[key], 1u);
    uint32_t slot = lbase[key] + rank;
    if (slot < ((uint32_t)key + 1u) * CAP)   // overflow guard (P ~ 1e-15)
      bins[slot] = make_uint2(ex, ey);
  }
}

// ---------------------------------------------------------------------------
// K4: one block (4 waves) per column, lane = b. Entries contiguous with exact
// count. Single visit per entry, one float2 gather (row pair). LDS reduce,
// 2 atomicAdds into pre-zeroed out.
// ---------------------------------------------------------------------------
__global__ __launch_bounds__(256) void accum_kernel(
    const uint32_t* __restrict__ colCnt, const uint2* __restrict__ bins,
    const float2* __restrict__ xP, float* __restrict__ out) {
  __shared__ float red_t[3][BB], red_n[3][BB];
  const int lane = threadIdx.x & 63;
  const int wv   = threadIdx.x >> 6;   // 0..3
  const int col  = blockIdx.x;

  int n = (int)colCnt[col];
  n = n < CAP ? n : CAP;
  const uint2* __restrict__ bin = bins + (size_t)col * CAP;

  // wave wv owns contiguous range [wv*q, min((wv+1)*q, n))
  const int q  = (n + 3) >> 2;
  const int e0 = wv * q;
  const int e1 = (e0 + q) < n ? (e0 + q) : n;

  float acc_t = 0.f, acc_n = 0.f;

#define PROC(Q)                                                           \
  {                                                                       \
    uint32_t ex_ = (Q).x, ey_ = (Q).y;                                    \
    int rowf = (int)(ex_ & 0xfffu);                                       \
    int rint = (int)((ex_ >> 12) & 1u);                                   \
    float wfr = __half2float(__ushort_as_half((ushort)(ex_ >> 16)));      \
    float2 p  = xP[(size_t)rowf * BB + lane];                             \
    float xc  = rint ? p.x : p.y;                                         \
    float wcr = rint ? 1.0f : 1.0f - wfr;                                 \
    float w_t = __half2float(__ushort_as_half((ushort)(ey_ & 0xffffu)));  \
    float w_n = __half2float(__ushort_as_half((ushort)(ey_ >> 16)));      \
    float term = fmaf(wfr, p.x, wcr * xc);                                \
    acc_t = fmaf(w_t, term, acc_t);                                       \
    acc_n = fmaf(w_n, term, acc_n);                                       \
  }

  int e = e0;
  for (; e + 8 <= e1; e += 8) {
    uint2 qv[8];
#pragma unroll
    for (int t = 0; t < 8; t++) qv[t] = bin[e + t];
#pragma unroll
    for (int t = 0; t < 8; t++) PROC(qv[t]);
  }
  for (; e < e1; e++) {
    uint2 qv = bin[e];
    PROC(qv)
  }
#undef PROC

  if (wv > 0) {
    red_t[wv - 1][lane] = acc_t;
    red_n[wv - 1][lane] = acc_n;
  }
  __syncthreads();
  if (wv == 0) {
    acc_t += red_t[0][lane] + red_t[1][lane] + red_t[2][lane];
    acc_n += red_n[0][lane] + red_n[1][lane] + red_n[2][lane];
    atomicAdd(&out[(size_t)col * BB + lane], acc_t);
    if (col + 1 < D_OUT) atomicAdd(&out[(size_t)(col + 1) * BB + lane], acc_n);
  }
}

// ---------------------------------------------------------------------------
// Fallback (ws too small / N too big): direct atomic scatter into out (f32).
// ---------------------------------------------------------------------------
__global__ __launch_bounds__(256) void direct_kernel(
    const float2* __restrict__ ind, const float* __restrict__ val,
    const float* __restrict__ x, float* __restrict__ out, int n) {
  int p = blockIdx.x * 4 + (threadIdx.x >> 6);
  if (p >= n) return;
  int lane = threadIdx.x & 63;
  float2 rc = ind[p];
  float v = val[p];
  float flr = floorf(rc.x), cer = ceilf(rc.x);
  float flc = floorf(rc.y), cec = ceilf(rc.y);
  float wfr = 1.0f - (rc.x - flr);
  float wcr = 1.0f - (cer - rc.x);
  float wfc = 1.0f - (rc.y - flc);
  float wcc = 1.0f - (cec - rc.y);
  float xf = x[(size_t)((int)flr) * BB + lane];
  float xc = x[(size_t)((int)cer) * BB + lane];
  float inner = fmaf(wfr, xf, wcr * xc);
  atomicAdd(&out[(size_t)((int)flc) * BB + lane], v * wfc * inner);
  atomicAdd(&out[(size_t)((int)cec) * BB + lane], v * wcc * inner);
}

// ---------------------------------------------------------------------------
extern "C" void kernel_launch(void* const* d_in, const int* in_sizes, int n_in,
                              void* d_out, int out_size, void* d_ws, size_t ws_size,
                              hipStream_t stream) {
  const float2* ind = (const float2*)d_in[0];   // [N,2] f32
  const float*  val = (const float*)d_in[1];    // [N]   f32
  const float*  x   = (const float*)d_in[2];    // [D_IN*B] f32
  float* out = (float*)d_out;                   // [D_OUT*B] f32
  const int N = in_sizes[1];

  const size_t hist_bytes = (size_t)NBLK * D_OUT * sizeof(uint32_t);      // 2 MB
  const size_t base_bytes = hist_bytes;                                   // 2 MB
  const size_t bin_bytes  = (size_t)D_OUT * CAP * sizeof(uint2);          // 4 MB
  const size_t xp_bytes   = (size_t)D_IN * BB * sizeof(float2);           // 2 MB
  const size_t cc_bytes   = (size_t)D_OUT * sizeof(uint32_t);             // 16 KB

  if (N <= NBLK * PPB &&
      ws_size >= hist_bytes + base_bytes + bin_bytes + xp_bytes + cc_bytes) {
    char* w = (char*)d_ws;
    uint32_t* hist   = (uint32_t*)w;                       w += hist_bytes;
    uint32_t* bases  = (uint32_t*)w;                       w += base_bytes;
    uint2*    bins   = (uint2*)w;                          w += bin_bytes;
    float2*   xP     = (float2*)w;                         w += xp_bytes;
    uint32_t* colCnt = (uint32_t*)w;

    hist_kernel<<<NBLK, 256, 0, stream>>>(ind, hist, N);
    scan_prep_kernel<<<16 + (D_OUT * BB + 255) / 256, 256, 0, stream>>>(
        hist, bases, colCnt, x, xP, out);
    scatter_kernel<<<NBLK, 256, 0, stream>>>(ind, val, bases, bins, N);
    accum_kernel<<<D_OUT, 256, 0, stream>>>(colCnt, bins, xP, out);
  } else {
    (void)hipMemsetAsync(out, 0, (size_t)out_size * sizeof(float), stream);
    direct_kernel<<<(N + 3) / 4, 256, 0, stream>>>(ind, val, x, out, N);
  }
}